// Round 1
// 870.355 us; speedup vs baseline: 1.1484x; 1.1484x over previous
//
#include <hip/hip_runtime.h>

#define NB 4
#define NL 2048
#define ND 512
#define NH 8
#define NTOK (NB * NL)  // 8192

constexpr float LN_EPS = 1e-5f;

typedef __attribute__((ext_vector_type(8))) short bf16x8;
typedef __attribute__((ext_vector_type(4))) float f32x4;

static __device__ __forceinline__ unsigned short f2bf(float f) {
  unsigned u = __builtin_bit_cast(unsigned, f);
  unsigned r = (u + 0x7fffu + ((u >> 16) & 1u)) >> 16;
  return (unsigned short)r;
}

static __device__ __forceinline__ uint2 pk4(const float4 f) {
  uint2 r;
  r.x = (unsigned)f2bf(f.x) | ((unsigned)f2bf(f.y) << 16);
  r.y = (unsigned)f2bf(f.z) | ((unsigned)f2bf(f.w) << 16);
  return r;
}

// ---------------------------------------------------------------------------
// MFMA GEMM (NT) core: C = X[m][c] * W[n][c], 64x64 tile, 256 threads (4 waves),
// BK=64, bf16 MFMA 16x16x32 with f32 accumulate. Staging converts f32->bf16.
// LDS rows padded to 72 ushort (144 B: 16B-aligned rows).
// Wave w owns m-rows [w*16, w*16+16); acc[nt] covers n-cols nt*16..+16.
// Fragment maps (m89/m91-verified): A/B [nonK=lane&15][K=quad*8+j],
// C/D [row=quad*4+reg][col=lane&15].
// ---------------------------------------------------------------------------
#define MFMA_GEMM_PRELUDE                                                      \
  __shared__ unsigned short As[64 * 72];                                       \
  __shared__ unsigned short Bs[64 * 72];                                       \
  const int tid = threadIdx.x;                                                 \
  const int w = tid >> 6;                                                      \
  const int lane = tid & 63;                                                   \
  const int quad = lane >> 4, l15 = lane & 15;                                 \
  const int m0 = blockIdx.x * 64, n0 = blockIdx.y * 64;                        \
  const int srow = tid >> 2;                                                   \
  const int c4 = (tid & 3) * 4;                                                \
  const int scol = (tid & 3) * 16;                                             \
  f32x4 acc[4];                                                                \
  acc[0] = acc[1] = acc[2] = acc[3] = (f32x4){0.f, 0.f, 0.f, 0.f};

#define MFMA_STEP(AV, BV)                                                      \
  do {                                                                         \
    __syncthreads();                                                           \
    _Pragma("unroll") for (int j = 0; j < 4; ++j) {                            \
      *(uint2*)&As[srow * 72 + c4 + j * 16] = pk4(AV[j]);                      \
      *(uint2*)&Bs[srow * 72 + c4 + j * 16] = pk4(BV[j]);                      \
    }                                                                          \
    __syncthreads();                                                           \
    _Pragma("unroll") for (int ks = 0; ks < 2; ++ks) {                         \
      const bf16x8 af = *(const bf16x8*)&As[(w * 16 + l15) * 72 + ks * 32 + quad * 8]; \
      _Pragma("unroll") for (int nt = 0; nt < 4; ++nt) {                       \
        const bf16x8 bfr = *(const bf16x8*)&Bs[(nt * 16 + l15) * 72 + ks * 32 + quad * 8]; \
        acc[nt] = __builtin_amdgcn_mfma_f32_16x16x32_bf16(af, bfr, acc[nt], 0, 0, 0); \
      }                                                                        \
    }                                                                          \
  } while (0)

// Projection for Q/K: out bf16 head-major [(b*8+h)*2048 + l][d], scaled.
__global__ __launch_bounds__(256) void gemm_qk_mfma(const float* __restrict__ X,
                                                    const float* __restrict__ W,
                                                    const float* __restrict__ bias,
                                                    unsigned short* __restrict__ out,
                                                    float scale) {
  MFMA_GEMM_PRELUDE
  for (int k0 = 0; k0 < 512; k0 += 64) {
    float4 av[4], bv[4];
#pragma unroll
    for (int j = 0; j < 4; ++j) {
      av[j] = *(const float4*)&X[(size_t)(m0 + srow) * ND + k0 + c4 + j * 16];
      bv[j] = *(const float4*)&W[(size_t)(n0 + srow) * ND + k0 + c4 + j * 16];
    }
    MFMA_STEP(av, bv);
  }
  // epilogue: bias+scale -> bf16 -> LDS bounce -> coalesced 16B stores
  const int hh = n0 >> 6;
  __syncthreads();
#pragma unroll
  for (int nt = 0; nt < 4; ++nt) {
    const float b = bias[n0 + nt * 16 + l15];
#pragma unroll
    for (int r = 0; r < 4; ++r)
      As[(w * 16 + quad * 4 + r) * 72 + nt * 16 + l15] = f2bf((acc[nt][r] + b) * scale);
  }
  __syncthreads();
  const int tok = m0 + srow;
  const int bb = tok >> 11, l = tok & 2047;
  unsigned short* orow = out + (((size_t)bb * NH + hh) * NL + l) * 64;
  *(uint4*)&orow[scol] = *(const uint4*)&As[srow * 72 + scol];
  *(uint4*)&orow[scol + 8] = *(const uint4*)&As[srow * 72 + scol + 8];
}

// Projection for V: out bf16 TRANSPOSED per head: [(b*8+h)*64 + d][l].
__global__ __launch_bounds__(256) void gemm_v_mfma_t(const float* __restrict__ X,
                                                     const float* __restrict__ W,
                                                     const float* __restrict__ bias,
                                                     unsigned short* __restrict__ outT) {
  MFMA_GEMM_PRELUDE
  for (int k0 = 0; k0 < 512; k0 += 64) {
    float4 av[4], bv[4];
#pragma unroll
    for (int j = 0; j < 4; ++j) {
      av[j] = *(const float4*)&X[(size_t)(m0 + srow) * ND + k0 + c4 + j * 16];
      bv[j] = *(const float4*)&W[(size_t)(n0 + srow) * ND + k0 + c4 + j * 16];
    }
    MFMA_STEP(av, bv);
  }
  // epilogue: transpose in LDS, then coalesced 16B stores along l
  const int hh = n0 >> 6;
  __syncthreads();
#pragma unroll
  for (int nt = 0; nt < 4; ++nt) {
    const float b = bias[n0 + nt * 16 + l15];
#pragma unroll
    for (int r = 0; r < 4; ++r)
      As[(nt * 16 + l15) * 72 + w * 16 + quad * 4 + r] = f2bf(acc[nt][r] + b);
  }
  __syncthreads();
  const int bb = m0 >> 11, l0 = m0 & 2047;
  unsigned short* orow = outT + (((size_t)bb * NH + hh) * 64 + srow) * NL + l0;
  *(uint4*)&orow[scol] = *(const uint4*)&As[srow * 72 + scol];
  *(uint4*)&orow[scol + 8] = *(const uint4*)&As[srow * 72 + scol + 8];
}

// ---------------------------------------------------------------------------
// MFMA attention (unchanged). Block = 4 waves; tile = 64 q x (b,h). Two passes:
//  P1: S = Q.K^T (mfma), mask (cached to VGPR bits), exp, rowsum.
//  P2: recompute S, p = exp(s)*inv, write attn, P->LDS(bf16), O += P.V (mfma).
// ---------------------------------------------------------------------------
__global__ __launch_bounds__(256) void attn_mfma(const unsigned short* __restrict__ qh,
                                                 const unsigned short* __restrict__ kh,
                                                 const unsigned short* __restrict__ vT,
                                                 const int* __restrict__ mask,
                                                 float* __restrict__ attn,
                                                 float* __restrict__ ao) {
  const int b = blockIdx.z, h = blockIdx.y, q0 = blockIdx.x * 64;
  const int bh = b * NH + h;
  __shared__ unsigned short Ks[64 * 72];
  __shared__ unsigned short Vt[64 * 72];
  __shared__ unsigned short Ps[4 * 16 * 72];  // per-wave 16x72 strips
  const int tid = threadIdx.x;
  const int w = tid >> 6, lane = tid & 63;
  const int quad = lane >> 4, l15 = lane & 15;

  const size_t qoff = ((size_t)bh * NL + q0 + w * 16 + l15) * 64 + quad * 8;
  const bf16x8 aq0 = *(const bf16x8*)(qh + qoff);
  const bf16x8 aq1 = *(const bf16x8*)(qh + qoff + 32);

  const int srow = tid >> 2;        // 0..63
  const int scol = (tid & 3) * 16;  // ushort offset {0,16,32,48}

  float rinv[4] = {0.f, 0.f, 0.f, 0.f};
  unsigned int mbits[16];
#pragma unroll
  for (int i = 0; i < 16; ++i) mbits[i] = 0;

  // ---------------- PASS 1 ----------------
  for (int kt = 0; kt < 32; ++kt) {
    const unsigned short* kg = kh + ((size_t)bh * NL + kt * 64 + srow) * 64 + scol;
    const uint4 k0 = *(const uint4*)kg;
    const uint4 k1 = *(const uint4*)(kg + 8);
    __syncthreads();
    *(uint4*)&Ks[srow * 72 + scol] = k0;
    *(uint4*)&Ks[srow * 72 + scol + 8] = k1;
    __syncthreads();
    f32x4 s[4];
#pragma unroll
    for (int nt = 0; nt < 4; ++nt) {
      const bf16x8 b0 = *(const bf16x8*)&Ks[(nt * 16 + l15) * 72 + quad * 8];
      const bf16x8 b1 = *(const bf16x8*)&Ks[(nt * 16 + l15) * 72 + 32 + quad * 8];
      f32x4 acc = {0.f, 0.f, 0.f, 0.f};
      acc = __builtin_amdgcn_mfma_f32_16x16x32_bf16(aq0, b0, acc, 0, 0, 0);
      acc = __builtin_amdgcn_mfma_f32_16x16x32_bf16(aq1, b1, acc, 0, 0, 0);
      s[nt] = acc;
    }
    unsigned int mb = 0;
#pragma unroll
    for (int r = 0; r < 4; ++r) {
      const size_t mrow = ((size_t)b * NL + q0 + w * 16 + quad * 4 + r) * NL + kt * 64;
#pragma unroll
      for (int nt = 0; nt < 4; ++nt) {
        const int mz = mask[mrow + nt * 16 + l15];
        float e = __expf(s[nt][r]);
        if (mz == 1) {
          mb |= (1u << (nt * 4 + r));
          e = 0.f;
        }
        rinv[r] += e;
      }
    }
    mbits[kt >> 1] |= mb << ((kt & 1) * 16);
  }
#pragma unroll
  for (int r = 0; r < 4; ++r) {
    float v = rinv[r];
    v += __shfl_xor(v, 1);
    v += __shfl_xor(v, 2);
    v += __shfl_xor(v, 4);
    v += __shfl_xor(v, 8);
    rinv[r] = 1.0f / v;
  }

  // ---------------- PASS 2 ----------------
  f32x4 oacc[4];
#pragma unroll
  for (int nt = 0; nt < 4; ++nt) oacc[nt] = (f32x4){0.f, 0.f, 0.f, 0.f};

  for (int kt = 0; kt < 32; ++kt) {
    const unsigned short* kg = kh + ((size_t)bh * NL + kt * 64 + srow) * 64 + scol;
    const unsigned short* vg = vT + ((size_t)bh * 64 + srow) * NL + kt * 64 + scol;
    const uint4 k0 = *(const uint4*)kg;
    const uint4 k1 = *(const uint4*)(kg + 8);
    const uint4 v0 = *(const uint4*)vg;
    const uint4 v1 = *(const uint4*)(vg + 8);
    __syncthreads();
    *(uint4*)&Ks[srow * 72 + scol] = k0;
    *(uint4*)&Ks[srow * 72 + scol + 8] = k1;
    *(uint4*)&Vt[srow * 72 + scol] = v0;
    *(uint4*)&Vt[srow * 72 + scol + 8] = v1;
    __syncthreads();
    f32x4 s[4];
#pragma unroll
    for (int nt = 0; nt < 4; ++nt) {
      const bf16x8 b0 = *(const bf16x8*)&Ks[(nt * 16 + l15) * 72 + quad * 8];
      const bf16x8 b1 = *(const bf16x8*)&Ks[(nt * 16 + l15) * 72 + 32 + quad * 8];
      f32x4 acc = {0.f, 0.f, 0.f, 0.f};
      acc = __builtin_amdgcn_mfma_f32_16x16x32_bf16(aq0, b0, acc, 0, 0, 0);
      acc = __builtin_amdgcn_mfma_f32_16x16x32_bf16(aq1, b1, acc, 0, 0, 0);
      s[nt] = acc;
    }
    const unsigned int mb = mbits[kt >> 1] >> ((kt & 1) * 16);
#pragma unroll
    for (int r = 0; r < 4; ++r) {
      const int q = q0 + w * 16 + quad * 4 + r;
      float* arow = attn + ((size_t)bh * NL + q) * NL + kt * 64;
      unsigned short* prow = &Ps[(w * 16 + quad * 4 + r) * 72];
#pragma unroll
      for (int nt = 0; nt < 4; ++nt) {
        float e = ((mb >> (nt * 4 + r)) & 1u) ? 0.f : __expf(s[nt][r]) * rinv[r];
        arow[nt * 16 + l15] = e;
        prow[nt * 16 + l15] = f2bf(e);
      }
    }
    const bf16x8 pa0 = *(const bf16x8*)&Ps[(w * 16 + l15) * 72 + quad * 8];
    const bf16x8 pa1 = *(const bf16x8*)&Ps[(w * 16 + l15) * 72 + 32 + quad * 8];
#pragma unroll
    for (int nt = 0; nt < 4; ++nt) {
      const bf16x8 vb0 = *(const bf16x8*)&Vt[(nt * 16 + l15) * 72 + quad * 8];
      const bf16x8 vb1 = *(const bf16x8*)&Vt[(nt * 16 + l15) * 72 + 32 + quad * 8];
      oacc[nt] = __builtin_amdgcn_mfma_f32_16x16x32_bf16(pa0, vb0, oacc[nt], 0, 0, 0);
      oacc[nt] = __builtin_amdgcn_mfma_f32_16x16x32_bf16(pa1, vb1, oacc[nt], 0, 0, 0);
    }
  }
#pragma unroll
  for (int r = 0; r < 4; ++r) {
    float* orow = ao + ((size_t)bh * NL + q0 + w * 16 + quad * 4 + r) * 64;
#pragma unroll
    for (int nt = 0; nt < 4; ++nt) orow[nt * 16 + l15] = oacc[nt][r];
  }
}

// ---------------------------------------------------------------------------
// fc (MFMA) with the faithful buffer-scramble gather on A + bias + residual.
// Gather math: for output token n and k-col c: h2,q2,b2,d2 as in reference.
// With BK=64 (64-aligned), q2/b2 depend only on k0; d2 spans c4+j*16 contiguously.
// ---------------------------------------------------------------------------
__global__ __launch_bounds__(256) void fc_gather_mfma(const float* __restrict__ AO,
                                                      const float* __restrict__ W,
                                                      const float* __restrict__ bias,
                                                      const float* __restrict__ resid,
                                                      float* __restrict__ Xout) {
  MFMA_GEMM_PRELUDE
  const int nrow = m0 + srow;
  const int b_out = nrow >> 11;
  const int l_out = nrow & 2047;
  const int h2 = b_out * 2 + (l_out >> 10);
  const int q2base = (l_out & 1023) << 1;
  for (int k0 = 0; k0 < 512; k0 += 64) {
    const int q2 = q2base | ((k0 >> 8) & 1);
    const int b2 = (k0 >> 6) & 3;
    const float* abase = AO + ((size_t)(h2 * 4 + b2) * NL + q2) * 64;
    float4 av[4], bv[4];
#pragma unroll
    for (int j = 0; j < 4; ++j) {
      av[j] = *(const float4*)&abase[c4 + j * 16];
      bv[j] = *(const float4*)&W[(size_t)(n0 + srow) * ND + k0 + c4 + j * 16];
    }
    MFMA_STEP(av, bv);
  }
  // epilogue: bias + residual, direct f32 stores (4x64B segments per instr)
#pragma unroll
  for (int nt = 0; nt < 4; ++nt) {
    const float b = bias[n0 + nt * 16 + l15];
#pragma unroll
    for (int r = 0; r < 4; ++r) {
      const int row = m0 + w * 16 + quad * 4 + r;
      const float rv = resid[(size_t)row * ND + n0 + nt * 16 + l15];
      Xout[(size_t)row * ND + n0 + nt * 16 + l15] = acc[nt][r] + b + rv;
    }
  }
}

// ---------------------------------------------------------------------------
// LayerNorm over last dim (512), one wave per token.
// ---------------------------------------------------------------------------
__global__ __launch_bounds__(64) void layernorm_k(const float* __restrict__ x,
                                                  const float* __restrict__ g,
                                                  const float* __restrict__ bta,
                                                  float* __restrict__ y) {
  const int n = blockIdx.x;
  const int lane = threadIdx.x;
  const float* row = x + (size_t)n * ND;
  const float4 a = *(const float4*)&row[lane * 8];
  const float4 c = *(const float4*)&row[lane * 8 + 4];
  float s = a.x + a.y + a.z + a.w + c.x + c.y + c.z + c.w;
  float sq = a.x * a.x + a.y * a.y + a.z * a.z + a.w * a.w +
             c.x * c.x + c.y * c.y + c.z * c.z + c.w * c.w;
#pragma unroll
  for (int off = 32; off; off >>= 1) {
    s += __shfl_down(s, off);
    sq += __shfl_down(sq, off);
  }
  s = __shfl(s, 0);
  sq = __shfl(sq, 0);
  const float mu = s * (1.f / 512.f);
  const float var = sq * (1.f / 512.f) - mu * mu;
  const float rstd = rsqrtf(var + LN_EPS);
  float* yo = y + (size_t)n * ND;
  const int c0 = lane * 8;
  float4 o1, o2;
  o1.x = (a.x - mu) * rstd * g[c0 + 0] + bta[c0 + 0];
  o1.y = (a.y - mu) * rstd * g[c0 + 1] + bta[c0 + 1];
  o1.z = (a.z - mu) * rstd * g[c0 + 2] + bta[c0 + 2];
  o1.w = (a.w - mu) * rstd * g[c0 + 3] + bta[c0 + 3];
  o2.x = (c.x - mu) * rstd * g[c0 + 4] + bta[c0 + 4];
  o2.y = (c.y - mu) * rstd * g[c0 + 5] + bta[c0 + 5];
  o2.z = (c.z - mu) * rstd * g[c0 + 6] + bta[c0 + 6];
  o2.w = (c.w - mu) * rstd * g[c0 + 7] + bta[c0 + 7];
  *(float4*)&yo[c0] = o1;
  *(float4*)&yo[c0 + 4] = o2;
}

extern "C" void kernel_launch(void* const* d_in, const int* in_sizes, int n_in,
                              void* d_out, int out_size, void* d_ws, size_t ws_size,
                              hipStream_t stream) {
  const float* q = (const float*)d_in[0];
  const float* k = (const float*)d_in[1];
  const float* v = (const float*)d_in[2];
  const int* mask = (const int*)d_in[3];
  const float* wq_w = (const float*)d_in[4];
  const float* wq_b = (const float*)d_in[5];
  const float* wv_w = (const float*)d_in[6];
  const float* wv_b = (const float*)d_in[7];
  const float* fc_w = (const float*)d_in[8];
  const float* fc_b = (const float*)d_in[9];
  const float* ln_g = (const float*)d_in[10];
  const float* ln_b = (const float*)d_in[11];

  float* y = (float*)d_out;
  float* attn = y + (size_t)NTOK * ND;  // second output, (B,H,L,L)

  const size_t SZ = (size_t)NTOK * ND;  // 4,194,304 elements
  unsigned short* qhb = (unsigned short*)d_ws;       // bf16 head-major, scaled
  unsigned short* khb = qhb + SZ;                    // bf16 head-major
  unsigned short* vTb = khb + SZ;                    // bf16 per-head transposed
  float* ao = (float*)(vTb + SZ);                    // attention out f32 (b,h,q,d)
  float* xx = ao + SZ;                               // fc out + residual

  const dim3 gproj(NTOK / 64, ND / 64);  // 128 x 8
  gemm_qk_mfma<<<gproj, 256, 0, stream>>>(q, wq_w, wq_b, qhb, 0.125f);
  gemm_qk_mfma<<<gproj, 256, 0, stream>>>(k, wq_w, wq_b, khb, 1.0f);
  gemm_v_mfma_t<<<gproj, 256, 0, stream>>>(v, wv_w, wv_b, vTb);
  attn_mfma<<<dim3(NL / 64, NH, NB), 256, 0, stream>>>(qhb, khb, vTb, mask, attn, ao);
  fc_gather_mfma<<<gproj, 256, 0, stream>>>(ao, fc_w, fc_b, q, xx);
  layernorm_k<<<NTOK, 64, 0, stream>>>(xx, ln_g, ln_b, y);
}

// Round 2
// 821.954 us; speedup vs baseline: 1.2160x; 1.0589x over previous
//
#include <hip/hip_runtime.h>

#define NB 4
#define NL 2048
#define ND 512
#define NH 8
#define NTOK (NB * NL)  // 8192

constexpr float LN_EPS = 1e-5f;

typedef __attribute__((ext_vector_type(8))) short bf16x8;
typedef __attribute__((ext_vector_type(4))) float f32x4;

static __device__ __forceinline__ unsigned short f2bf(float f) {
  unsigned u = __builtin_bit_cast(unsigned, f);
  unsigned r = (u + 0x7fffu + ((u >> 16) & 1u)) >> 16;
  return (unsigned short)r;
}

static __device__ __forceinline__ uint2 pk4(const float4 f) {
  uint2 r;
  r.x = (unsigned)f2bf(f.x) | ((unsigned)f2bf(f.y) << 16);
  r.y = (unsigned)f2bf(f.z) | ((unsigned)f2bf(f.w) << 16);
  return r;
}

// ---------------------------------------------------------------------------
// f32 -> bf16 bulk convert: 3 arrays selected by blockIdx.y, 8 elems/thread.
// ---------------------------------------------------------------------------
__global__ __launch_bounds__(256) void cvt3_bf16(const float* __restrict__ s0,
                                                 const float* __restrict__ s1,
                                                 const float* __restrict__ s2,
                                                 unsigned short* __restrict__ d0,
                                                 unsigned short* __restrict__ d1,
                                                 unsigned short* __restrict__ d2) {
  const float* s = (blockIdx.y == 0) ? s0 : (blockIdx.y == 1) ? s1 : s2;
  unsigned short* d = (blockIdx.y == 0) ? d0 : (blockIdx.y == 1) ? d1 : d2;
  const size_t i = ((size_t)blockIdx.x * 256 + threadIdx.x) * 8;
  const float4 a = *(const float4*)&s[i];
  const float4 b = *(const float4*)&s[i + 4];
  uint4 o;
  const uint2 lo = pk4(a), hi = pk4(b);
  o.x = lo.x; o.y = lo.y; o.z = hi.x; o.w = hi.y;
  *(uint4*)&d[i] = o;
}

// ---------------------------------------------------------------------------
// Pack mask (B,L,L) int32{0,1} -> bit qwords [b][q][kt] (kt = k/64, bit j = k%64).
// One wave per qword via ballot.
// ---------------------------------------------------------------------------
__global__ __launch_bounds__(256) void pack_mask(const int* __restrict__ mask,
                                                 unsigned long long* __restrict__ mpk) {
  const int w = threadIdx.x >> 6, lane = threadIdx.x & 63;
  const size_t g = (size_t)blockIdx.x * 4 + w;
  const int m = mask[g * 64 + lane];
  const unsigned long long bits = __ballot(m == 1);
  if (lane == 0) mpk[g] = bits;
}

// ---------------------------------------------------------------------------
// bf16 MFMA GEMM (NT) core: C = X[m][c] * W[n][c], both operands pre-converted
// bf16. 64x64 tile, 256 threads (4 waves), BK=64. LDS rows padded to 72 ushort
// (144 B -> rows stride 4 banks; 2 lanes/bank on b128 reads = conflict-free).
// Fragment maps (m89/m91-verified): A/B [nonK=lane&15][K=quad*8+j],
// C/D [row=quad*4+reg][col=lane&15].
// ---------------------------------------------------------------------------
#define BF16_GEMM_PRELUDE                                                      \
  __shared__ unsigned short As[64 * 72];                                       \
  __shared__ unsigned short Bs[64 * 72];                                       \
  const int tid = threadIdx.x;                                                 \
  const int w = tid >> 6;                                                      \
  const int lane = tid & 63;                                                   \
  const int quad = lane >> 4, l15 = lane & 15;                                 \
  const int m0 = blockIdx.x * 64, n0 = blockIdx.y * 64;                        \
  const int srow = tid >> 2;                                                   \
  const int scol = (tid & 3) * 16;                                             \
  f32x4 acc[4];                                                                \
  acc[0] = acc[1] = acc[2] = acc[3] = (f32x4){0.f, 0.f, 0.f, 0.f};

#define BF16_GEMM_STEP(ap, bp)                                                 \
  do {                                                                         \
    const uint4 a0 = *(const uint4*)((ap));                                    \
    const uint4 a1 = *(const uint4*)((ap) + 8);                                \
    const uint4 b0 = *(const uint4*)((bp));                                    \
    const uint4 b1 = *(const uint4*)((bp) + 8);                                \
    __syncthreads();                                                           \
    *(uint4*)&As[srow * 72 + scol] = a0;                                       \
    *(uint4*)&As[srow * 72 + scol + 8] = a1;                                   \
    *(uint4*)&Bs[srow * 72 + scol] = b0;                                       \
    *(uint4*)&Bs[srow * 72 + scol + 8] = b1;                                   \
    __syncthreads();                                                           \
    _Pragma("unroll") for (int ks = 0; ks < 2; ++ks) {                         \
      const bf16x8 af = *(const bf16x8*)&As[(w * 16 + l15) * 72 + ks * 32 + quad * 8]; \
      _Pragma("unroll") for (int nt = 0; nt < 4; ++nt) {                       \
        const bf16x8 bfr = *(const bf16x8*)&Bs[(nt * 16 + l15) * 72 + ks * 32 + quad * 8]; \
        acc[nt] = __builtin_amdgcn_mfma_f32_16x16x32_bf16(af, bfr, acc[nt], 0, 0, 0); \
      }                                                                        \
    }                                                                          \
  } while (0)

// Projection for Q/K: out bf16 head-major [(b*8+h)*2048 + l][d], scaled.
__global__ __launch_bounds__(256) void gemm_qk_mfma(const unsigned short* __restrict__ X,
                                                    const unsigned short* __restrict__ W,
                                                    const float* __restrict__ bias,
                                                    unsigned short* __restrict__ out,
                                                    float scale) {
  BF16_GEMM_PRELUDE
  for (int k0 = 0; k0 < 512; k0 += 64) {
    const unsigned short* ap = X + (size_t)(m0 + srow) * ND + k0 + scol;
    const unsigned short* bp = W + (size_t)(n0 + srow) * ND + k0 + scol;
    BF16_GEMM_STEP(ap, bp);
  }
  // epilogue: bias+scale -> bf16 -> LDS bounce -> coalesced 16B stores
  const int hh = n0 >> 6;
  __syncthreads();
#pragma unroll
  for (int nt = 0; nt < 4; ++nt) {
    const float b = bias[n0 + nt * 16 + l15];
#pragma unroll
    for (int r = 0; r < 4; ++r)
      As[(w * 16 + quad * 4 + r) * 72 + nt * 16 + l15] = f2bf((acc[nt][r] + b) * scale);
  }
  __syncthreads();
  const int tok = m0 + srow;
  const int bb = tok >> 11, l = tok & 2047;
  unsigned short* orow = out + (((size_t)bb * NH + hh) * NL + l) * 64;
  *(uint4*)&orow[scol] = *(const uint4*)&As[srow * 72 + scol];
  *(uint4*)&orow[scol + 8] = *(const uint4*)&As[srow * 72 + scol + 8];
}

// Projection for V: out bf16 TRANSPOSED per head: [(b*8+h)*64 + d][l].
__global__ __launch_bounds__(256) void gemm_v_mfma_t(const unsigned short* __restrict__ X,
                                                     const unsigned short* __restrict__ W,
                                                     const float* __restrict__ bias,
                                                     unsigned short* __restrict__ outT) {
  BF16_GEMM_PRELUDE
  for (int k0 = 0; k0 < 512; k0 += 64) {
    const unsigned short* ap = X + (size_t)(m0 + srow) * ND + k0 + scol;
    const unsigned short* bp = W + (size_t)(n0 + srow) * ND + k0 + scol;
    BF16_GEMM_STEP(ap, bp);
  }
  // epilogue: transpose in LDS, then coalesced 16B stores along l
  const int hh = n0 >> 6;
  __syncthreads();
#pragma unroll
  for (int nt = 0; nt < 4; ++nt) {
    const float b = bias[n0 + nt * 16 + l15];
#pragma unroll
    for (int r = 0; r < 4; ++r)
      As[(nt * 16 + l15) * 72 + w * 16 + quad * 4 + r] = f2bf(acc[nt][r] + b);
  }
  __syncthreads();
  const int bb = m0 >> 11, l0 = m0 & 2047;
  unsigned short* orow = outT + (((size_t)bb * NH + hh) * 64 + srow) * NL + l0;
  *(uint4*)&orow[scol] = *(const uint4*)&As[srow * 72 + scol];
  *(uint4*)&orow[scol + 8] = *(const uint4*)&As[srow * 72 + scol + 8];
}

// ---------------------------------------------------------------------------
// MFMA attention. Block = 4 waves; tile = 64 q x (b,h). Two passes:
//  P1: S = Q.K^T (mfma), packed-mask bits -> VGPR, exp, rowsum.
//  P2: recompute S, p = exp(s)*inv, write attn, P->LDS(bf16), O += P.V (mfma).
// ao written as bf16 (fc consumes bf16; identical rounding to before).
// ---------------------------------------------------------------------------
__global__ __launch_bounds__(256) void attn_mfma(const unsigned short* __restrict__ qh,
                                                 const unsigned short* __restrict__ kh,
                                                 const unsigned short* __restrict__ vT,
                                                 const unsigned long long* __restrict__ mpk,
                                                 float* __restrict__ attn,
                                                 unsigned short* __restrict__ ao) {
  const int b = blockIdx.z, h = blockIdx.y, q0 = blockIdx.x * 64;
  const int bh = b * NH + h;
  __shared__ unsigned short Ks[64 * 72];
  __shared__ unsigned short Vt[64 * 72];
  __shared__ unsigned short Ps[4 * 16 * 72];  // per-wave 16x72 strips
  const int tid = threadIdx.x;
  const int w = tid >> 6, lane = tid & 63;
  const int quad = lane >> 4, l15 = lane & 15;

  const size_t qoff = ((size_t)bh * NL + q0 + w * 16 + l15) * 64 + quad * 8;
  const bf16x8 aq0 = *(const bf16x8*)(qh + qoff);
  const bf16x8 aq1 = *(const bf16x8*)(qh + qoff + 32);

  const int srow = tid >> 2;        // 0..63
  const int scol = (tid & 3) * 16;  // ushort offset {0,16,32,48}

  // packed-mask row base for this thread's 4 q-rows (quad*4 + r)
  const size_t mrowq = ((size_t)b * NL + q0 + w * 16 + quad * 4) * 32;

  float rinv[4] = {0.f, 0.f, 0.f, 0.f};
  unsigned int mbits[16];
#pragma unroll
  for (int i = 0; i < 16; ++i) mbits[i] = 0;

  // ---------------- PASS 1 ----------------
  for (int kt = 0; kt < 32; ++kt) {
    const unsigned short* kg = kh + ((size_t)bh * NL + kt * 64 + srow) * 64 + scol;
    const uint4 k0 = *(const uint4*)kg;
    const uint4 k1 = *(const uint4*)(kg + 8);
    unsigned long long mq[4];
#pragma unroll
    for (int r = 0; r < 4; ++r) mq[r] = mpk[mrowq + (size_t)r * 32 + kt];
    __syncthreads();
    *(uint4*)&Ks[srow * 72 + scol] = k0;
    *(uint4*)&Ks[srow * 72 + scol + 8] = k1;
    __syncthreads();
    f32x4 s[4];
#pragma unroll
    for (int nt = 0; nt < 4; ++nt) {
      const bf16x8 b0 = *(const bf16x8*)&Ks[(nt * 16 + l15) * 72 + quad * 8];
      const bf16x8 b1 = *(const bf16x8*)&Ks[(nt * 16 + l15) * 72 + 32 + quad * 8];
      f32x4 acc = {0.f, 0.f, 0.f, 0.f};
      acc = __builtin_amdgcn_mfma_f32_16x16x32_bf16(aq0, b0, acc, 0, 0, 0);
      acc = __builtin_amdgcn_mfma_f32_16x16x32_bf16(aq1, b1, acc, 0, 0, 0);
      s[nt] = acc;
    }
    unsigned int mb = 0;
#pragma unroll
    for (int r = 0; r < 4; ++r) {
      const unsigned long long t = mq[r] >> l15;
      mb |= ((unsigned)t & 1u) << (0 + r);
      mb |= (((unsigned)t >> 16) & 1u) << (4 + r);
      mb |= (((unsigned)(t >> 32)) & 1u) << (8 + r);
      mb |= (((unsigned)(t >> 48)) & 1u) << (12 + r);
    }
#pragma unroll
    for (int r = 0; r < 4; ++r) {
#pragma unroll
      for (int nt = 0; nt < 4; ++nt) {
        const float e = ((mb >> (nt * 4 + r)) & 1u) ? 0.f : __expf(s[nt][r]);
        rinv[r] += e;
      }
    }
    mbits[kt >> 1] |= mb << ((kt & 1) * 16);
  }
#pragma unroll
  for (int r = 0; r < 4; ++r) {
    float v = rinv[r];
    v += __shfl_xor(v, 1);
    v += __shfl_xor(v, 2);
    v += __shfl_xor(v, 4);
    v += __shfl_xor(v, 8);
    rinv[r] = 1.0f / v;
  }

  // ---------------- PASS 2 ----------------
  f32x4 oacc[4];
#pragma unroll
  for (int nt = 0; nt < 4; ++nt) oacc[nt] = (f32x4){0.f, 0.f, 0.f, 0.f};

  for (int kt = 0; kt < 32; ++kt) {
    const unsigned short* kg = kh + ((size_t)bh * NL + kt * 64 + srow) * 64 + scol;
    const unsigned short* vg = vT + ((size_t)bh * 64 + srow) * NL + kt * 64 + scol;
    const uint4 k0 = *(const uint4*)kg;
    const uint4 k1 = *(const uint4*)(kg + 8);
    const uint4 v0 = *(const uint4*)vg;
    const uint4 v1 = *(const uint4*)(vg + 8);
    __syncthreads();
    *(uint4*)&Ks[srow * 72 + scol] = k0;
    *(uint4*)&Ks[srow * 72 + scol + 8] = k1;
    *(uint4*)&Vt[srow * 72 + scol] = v0;
    *(uint4*)&Vt[srow * 72 + scol + 8] = v1;
    __syncthreads();
    f32x4 s[4];
#pragma unroll
    for (int nt = 0; nt < 4; ++nt) {
      const bf16x8 b0 = *(const bf16x8*)&Ks[(nt * 16 + l15) * 72 + quad * 8];
      const bf16x8 b1 = *(const bf16x8*)&Ks[(nt * 16 + l15) * 72 + 32 + quad * 8];
      f32x4 acc = {0.f, 0.f, 0.f, 0.f};
      acc = __builtin_amdgcn_mfma_f32_16x16x32_bf16(aq0, b0, acc, 0, 0, 0);
      acc = __builtin_amdgcn_mfma_f32_16x16x32_bf16(aq1, b1, acc, 0, 0, 0);
      s[nt] = acc;
    }
    const unsigned int mb = mbits[kt >> 1] >> ((kt & 1) * 16);
#pragma unroll
    for (int r = 0; r < 4; ++r) {
      const int q = q0 + w * 16 + quad * 4 + r;
      float* arow = attn + ((size_t)bh * NL + q) * NL + kt * 64;
      unsigned short* prow = &Ps[(w * 16 + quad * 4 + r) * 72];
#pragma unroll
      for (int nt = 0; nt < 4; ++nt) {
        float e = ((mb >> (nt * 4 + r)) & 1u) ? 0.f : __expf(s[nt][r]) * rinv[r];
        arow[nt * 16 + l15] = e;
        prow[nt * 16 + l15] = f2bf(e);
      }
    }
    const bf16x8 pa0 = *(const bf16x8*)&Ps[(w * 16 + l15) * 72 + quad * 8];
    const bf16x8 pa1 = *(const bf16x8*)&Ps[(w * 16 + l15) * 72 + 32 + quad * 8];
#pragma unroll
    for (int nt = 0; nt < 4; ++nt) {
      const bf16x8 vb0 = *(const bf16x8*)&Vt[(nt * 16 + l15) * 72 + quad * 8];
      const bf16x8 vb1 = *(const bf16x8*)&Vt[(nt * 16 + l15) * 72 + 32 + quad * 8];
      oacc[nt] = __builtin_amdgcn_mfma_f32_16x16x32_bf16(pa0, vb0, oacc[nt], 0, 0, 0);
      oacc[nt] = __builtin_amdgcn_mfma_f32_16x16x32_bf16(pa1, vb1, oacc[nt], 0, 0, 0);
    }
  }
  // epilogue: oacc -> bf16 via per-wave Ps strip -> coalesced 16B stores
#pragma unroll
  for (int nt = 0; nt < 4; ++nt)
#pragma unroll
    for (int r = 0; r < 4; ++r)
      Ps[(w * 16 + quad * 4 + r) * 72 + nt * 16 + l15] = f2bf(oacc[nt][r]);
  // same-wave LDS RAW: no barrier needed
  const int erow = lane >> 2;          // 0..15 within wave strip
  const int ecol = (lane & 3) * 16;    // 0,16,32,48
  unsigned short* orow = ao + (((size_t)bh * NL + q0 + w * 16 + erow) * 64) + ecol;
  *(uint4*)&orow[0] = *(const uint4*)&Ps[(w * 16 + erow) * 72 + ecol];
  *(uint4*)&orow[8] = *(const uint4*)&Ps[(w * 16 + erow) * 72 + ecol + 8];
}

// ---------------------------------------------------------------------------
// fc (MFMA, bf16 operands) with the faithful buffer-scramble gather on A
// + bias + residual. With BK=64 (64-aligned), q2/b2 depend only on k0.
// ---------------------------------------------------------------------------
__global__ __launch_bounds__(256) void fc_gather_mfma(const unsigned short* __restrict__ AO,
                                                      const unsigned short* __restrict__ W,
                                                      const float* __restrict__ bias,
                                                      const float* __restrict__ resid,
                                                      float* __restrict__ Xout) {
  BF16_GEMM_PRELUDE
  const int nrow = m0 + srow;
  const int b_out = nrow >> 11;
  const int l_out = nrow & 2047;
  const int h2 = b_out * 2 + (l_out >> 10);
  const int q2base = (l_out & 1023) << 1;
  for (int k0 = 0; k0 < 512; k0 += 64) {
    const int q2 = q2base | ((k0 >> 8) & 1);
    const int b2 = (k0 >> 6) & 3;
    const unsigned short* ap = AO + ((size_t)(h2 * 4 + b2) * NL + q2) * 64 + scol;
    const unsigned short* bp = W + (size_t)(n0 + srow) * ND + k0 + scol;
    BF16_GEMM_STEP(ap, bp);
  }
  // epilogue: bias + residual, direct f32 stores (4x64B segments per instr)
#pragma unroll
  for (int nt = 0; nt < 4; ++nt) {
    const float b = bias[n0 + nt * 16 + l15];
#pragma unroll
    for (int r = 0; r < 4; ++r) {
      const int row = m0 + w * 16 + quad * 4 + r;
      const float rv = resid[(size_t)row * ND + n0 + nt * 16 + l15];
      Xout[(size_t)row * ND + n0 + nt * 16 + l15] = acc[nt][r] + b + rv;
    }
  }
}

// ---------------------------------------------------------------------------
// LayerNorm over last dim (512), one wave per token.
// ---------------------------------------------------------------------------
__global__ __launch_bounds__(64) void layernorm_k(const float* __restrict__ x,
                                                  const float* __restrict__ g,
                                                  const float* __restrict__ bta,
                                                  float* __restrict__ y) {
  const int n = blockIdx.x;
  const int lane = threadIdx.x;
  const float* row = x + (size_t)n * ND;
  const float4 a = *(const float4*)&row[lane * 8];
  const float4 c = *(const float4*)&row[lane * 8 + 4];
  float s = a.x + a.y + a.z + a.w + c.x + c.y + c.z + c.w;
  float sq = a.x * a.x + a.y * a.y + a.z * a.z + a.w * a.w +
             c.x * c.x + c.y * c.y + c.z * c.z + c.w * c.w;
#pragma unroll
  for (int off = 32; off; off >>= 1) {
    s += __shfl_down(s, off);
    sq += __shfl_down(sq, off);
  }
  s = __shfl(s, 0);
  sq = __shfl(sq, 0);
  const float mu = s * (1.f / 512.f);
  const float var = sq * (1.f / 512.f) - mu * mu;
  const float rstd = rsqrtf(var + LN_EPS);
  float* yo = y + (size_t)n * ND;
  const int c0 = lane * 8;
  float4 o1, o2;
  o1.x = (a.x - mu) * rstd * g[c0 + 0] + bta[c0 + 0];
  o1.y = (a.y - mu) * rstd * g[c0 + 1] + bta[c0 + 1];
  o1.z = (a.z - mu) * rstd * g[c0 + 2] + bta[c0 + 2];
  o1.w = (a.w - mu) * rstd * g[c0 + 3] + bta[c0 + 3];
  o2.x = (c.x - mu) * rstd * g[c0 + 4] + bta[c0 + 4];
  o2.y = (c.y - mu) * rstd * g[c0 + 5] + bta[c0 + 5];
  o2.z = (c.z - mu) * rstd * g[c0 + 6] + bta[c0 + 6];
  o2.w = (c.w - mu) * rstd * g[c0 + 7] + bta[c0 + 7];
  *(float4*)&yo[c0] = o1;
  *(float4*)&yo[c0 + 4] = o2;
}

extern "C" void kernel_launch(void* const* d_in, const int* in_sizes, int n_in,
                              void* d_out, int out_size, void* d_ws, size_t ws_size,
                              hipStream_t stream) {
  const float* q = (const float*)d_in[0];
  const float* k = (const float*)d_in[1];
  const float* v = (const float*)d_in[2];
  const int* mask = (const int*)d_in[3];
  const float* wq_w = (const float*)d_in[4];
  const float* wq_b = (const float*)d_in[5];
  const float* wv_w = (const float*)d_in[6];
  const float* wv_b = (const float*)d_in[7];
  const float* fc_w = (const float*)d_in[8];
  const float* fc_b = (const float*)d_in[9];
  const float* ln_g = (const float*)d_in[10];
  const float* ln_b = (const float*)d_in[11];

  float* y = (float*)d_out;
  float* attn = y + (size_t)NTOK * ND;  // second output, (B,H,L,L)

  const size_t SZ = (size_t)NTOK * ND;   // 4,194,304 elements
  const size_t WSZ = (size_t)ND * ND;    // 262,144 elements
  unsigned short* qhb = (unsigned short*)d_ws;  // bf16 head-major, scaled
  unsigned short* khb = qhb + SZ;               // bf16 head-major
  unsigned short* vTb = khb + SZ;               // bf16 per-head transposed
  unsigned short* aob = vTb + SZ;               // attention out bf16 (b,h,q,d)
  unsigned short* qb = aob + SZ;                // bf16 inputs
  unsigned short* kb = qb + SZ;
  unsigned short* vb = kb + SZ;
  float* xx = (float*)(vb + SZ);                // fc out + residual (f32)
  unsigned short* wqb = (unsigned short*)(xx + SZ);
  unsigned short* wvb = wqb + WSZ;
  unsigned short* fcwb = wvb + WSZ;
  unsigned long long* mpk = (unsigned long long*)(fcwb + WSZ);  // packed mask

  cvt3_bf16<<<dim3(SZ / 2048, 3), 256, 0, stream>>>(q, k, v, qb, kb, vb);
  cvt3_bf16<<<dim3(WSZ / 2048, 3), 256, 0, stream>>>(wq_w, wv_w, fc_w, wqb, wvb, fcwb);
  pack_mask<<<(NB * NL * 32) / 4, 256, 0, stream>>>(mask, mpk);

  const dim3 gproj(NTOK / 64, ND / 64);  // 128 x 8
  gemm_qk_mfma<<<gproj, 256, 0, stream>>>(qb, wqb, wq_b, qhb, 0.125f);
  gemm_qk_mfma<<<gproj, 256, 0, stream>>>(kb, wqb, wq_b, khb, 1.0f);
  gemm_v_mfma_t<<<gproj, 256, 0, stream>>>(vb, wvb, wv_b, vTb);
  attn_mfma<<<dim3(NL / 64, NH, NB), 256, 0, stream>>>(qhb, khb, vTb, mpk, attn, aob);
  fc_gather_mfma<<<gproj, 256, 0, stream>>>(aob, fcwb, fc_b, q, xx);
  layernorm_k<<<NTOK, 64, 0, stream>>>(xx, ln_g, ln_b, y);
}